// Round 2
// baseline (80.977 us; speedup 1.0000x reference)
//
#include <hip/hip_runtime.h>

// FVNet: B=8, F=512, N=512, K=32, fp32.
// Round 6: occupancy push. Both kernels were latency-bound at 1-2 waves/SIMD
// (256/512 blocks on 256 CUs), with barrier drains and LDS latency fully
// exposed. Halve per-block tiles to double grids:
//   k_a:    8-n tiles  -> 512 blocks (2 blocks/CU, 2 waves/SIMD)
//   k_axfv: 4-f tiles  -> 1024 blocks (4 blocks/CU, 4 waves/SIMD)
// W staging/extraction path in k_a is identical to the verified R4 kernel.
//
// Per-b global l2norm == 1/sqrt(512) analytically: all 512 K-rows are
// unit-norm after the first normalization and row norms are O(10), never
// near the 1e-12 clamp.
// ws floats: aP[131072] | asumP[16384]

#define B_ 8
#define F_ 512
#define N_ 512
#define K_ 32

// ---------------- K1: logits + softmax + a + asumP ----------------
// grid = B * 64 ntiles (8 n) = 512 blocks, 256 threads.
// Threads: fs = t>>4 (16-way f-split), kg = (t>>2)&3 (8 k), ng = t&3 (2 n).
__global__ __launch_bounds__(256) void k_a(const float* __restrict__ x,
                                           const float* __restrict__ W,
                                           const float* __restrict__ bias,
                                           float* __restrict__ aP,
                                           float* __restrict__ asumP) {
  __shared__ float xs[128 * 10];    // [f][n] stride 10 (2-way max, free)
  __shared__ float ws[128 * 32];    // [f][k ^ (f&31)] XOR-swizzled, no pad
  __shared__ float red2[16 * 260];  // [fs][row*32+k] partial dump
  __shared__ float sm4[4][32];      // per-wave asum partials
  const int t = threadIdx.x;
  const int b  = blockIdx.x >> 6;
  const int nt = blockIdx.x & 63;
  const int n0 = nt << 3;
  const int ng = t & 3;
  const int kg = (t >> 2) & 3;
  const int fs = t >> 4;
  const int n2 = ng * 2;
  const int k8 = kg * 8;

  float acc[2][8];
#pragma unroll
  for (int i = 0; i < 2; ++i)
#pragma unroll
    for (int j = 0; j < 8; ++j) acc[i][j] = 0.f;

  float xr[4], wr[16];
  // ---- prefetch + store phase 0 ----
#pragma unroll
  for (int it = 0; it < 4; ++it) {
    int flat = t + 256 * it;
    xr[it] = x[(size_t)(b * F_ + (flat >> 3)) * N_ + n0 + (flat & 7)];
  }
#pragma unroll
  for (int it = 0; it < 16; ++it) {
    int flat = t + 256 * it;
    wr[it] = W[(flat >> 7) * F_ + (flat & 127)];
  }
#pragma unroll
  for (int it = 0; it < 4; ++it) {
    int flat = t + 256 * it;
    xs[(flat >> 3) * 10 + (flat & 7)] = xr[it];
  }
#pragma unroll
  for (int it = 0; it < 16; ++it) {
    int flat = t + 256 * it;
    int f = flat & 127, k = flat >> 7;
    ws[f * 32 + (k ^ (f & 31))] = wr[it];
  }
  __syncthreads();

  for (int ph = 0; ph < 4; ++ph) {
    if (ph < 3) {   // prefetch next phase into registers
      const int fb = (ph + 1) << 7;
#pragma unroll
      for (int it = 0; it < 4; ++it) {
        int flat = t + 256 * it;
        xr[it] = x[(size_t)(b * F_ + fb + (flat >> 3)) * N_ + n0 + (flat & 7)];
      }
#pragma unroll
      for (int it = 0; it < 16; ++it) {
        int flat = t + 256 * it;
        wr[it] = W[(flat >> 7) * F_ + fb + (flat & 127)];
      }
    }
#pragma unroll
    for (int fi = 0; fi < 8; ++fi) {
      const int f = fs * 8 + fi;
      const float2 x01 = *(const float2*)&xs[f * 10 + n2];
      const float4 wA = *(const float4*)&ws[f * 32 + ((k8) ^ (f & 28))];
      const float4 wB = *(const float4*)&ws[f * 32 + ((k8 + 4) ^ (f & 28))];
      const float xv[2] = {x01.x, x01.y};
      const float wa[4] = {((const float*)&wA)[0 ^ (fi & 3)],
                           ((const float*)&wA)[1 ^ (fi & 3)],
                           ((const float*)&wA)[2 ^ (fi & 3)],
                           ((const float*)&wA)[3 ^ (fi & 3)]};
      const float wb[4] = {((const float*)&wB)[0 ^ (fi & 3)],
                           ((const float*)&wB)[1 ^ (fi & 3)],
                           ((const float*)&wB)[2 ^ (fi & 3)],
                           ((const float*)&wB)[3 ^ (fi & 3)]};
#pragma unroll
      for (int i = 0; i < 2; ++i)
#pragma unroll
        for (int j = 0; j < 4; ++j) {
          acc[i][j]     += xv[i] * wa[j];
          acc[i][4 + j] += xv[i] * wb[j];
        }
    }
    __syncthreads();
    if (ph < 3) {
#pragma unroll
      for (int it = 0; it < 4; ++it) {
        int flat = t + 256 * it;
        xs[(flat >> 3) * 10 + (flat & 7)] = xr[it];
      }
#pragma unroll
      for (int it = 0; it < 16; ++it) {
        int flat = t + 256 * it;
        int f = flat & 127, k = flat >> 7;
        ws[f * 32 + (k ^ (f & 31))] = wr[it];
      }
      __syncthreads();
    }
  }

  // ---- dump partials ----
#pragma unroll
  for (int i = 0; i < 2; ++i) {
    float4 v1, v2;
    v1.x = acc[i][0]; v1.y = acc[i][1]; v1.z = acc[i][2]; v1.w = acc[i][3];
    v2.x = acc[i][4]; v2.y = acc[i][5]; v2.z = acc[i][6]; v2.w = acc[i][7];
    *(float4*)&red2[fs * 260 + (n2 + i) * 32 + k8] = v1;
    *(float4*)&red2[fs * 260 + (n2 + i) * 32 + k8 + 4] = v2;
  }
  __syncthreads();

  // ---- combine 16 f-splits; thread owns output (row = t>>5, k = t&31) ----
  const int k = t & 31;
  const int row = t >> 5;
  float l = bias[k];
#pragma unroll
  for (int s2 = 0; s2 < 16; ++s2) l += red2[s2 * 260 + t];  // row*32+k == t

  // ---- softmax over 32 k (width-32 shuffles) ----
  float m = l;
  m = fmaxf(m, __shfl_xor(m, 1, 32));
  m = fmaxf(m, __shfl_xor(m, 2, 32));
  m = fmaxf(m, __shfl_xor(m, 4, 32));
  m = fmaxf(m, __shfl_xor(m, 8, 32));
  m = fmaxf(m, __shfl_xor(m, 16, 32));
  const float e = __expf(l - m);
  float ssum = e;
  ssum += __shfl_xor(ssum, 1, 32);
  ssum += __shfl_xor(ssum, 2, 32);
  ssum += __shfl_xor(ssum, 4, 32);
  ssum += __shfl_xor(ssum, 8, 32);
  ssum += __shfl_xor(ssum, 16, 32);
  const float a0 = e * (1.f / ssum);
  aP[(size_t)(b * N_ + n0 + row) * K_ + k] = a0;

  // ---- asum partials over the 8 rows ----
  float s0 = a0 + __shfl_xor(a0, 32);   // row pair within wave
  const int l6 = t & 63, w = t >> 6;
  if (l6 < 32) sm4[w][l6] = s0;
  __syncthreads();
  if (t < 32) {
    float tot = sm4[0][t] + sm4[1][t] + sm4[2][t] + sm4[3][t];
    asumP[(b * 64 + nt) * 32 + t] = tot;
  }
}

// ---------------- K2: ax/ax2 GEMMs + fv epilogue (fused) ----------------
// grid = B * 128 ftiles (4 f) = 1024 blocks (4 blocks/CU), 256 threads.
// Main loop threads: ns = t>>4 (16-way n-split), fg = (t>>3)&1 (2 f),
// kg = t&7 (4 k); 16 accumulators/thread over 32 n each (4 chunks x 8).
// Epilogue: LDS-reduce the 16 ns-partials, fv math, 32-lane k-norm, store.
__global__ __launch_bounds__(256) void k_axfv(const float* __restrict__ x,
                                              const float* __restrict__ aP,
                                              const float* __restrict__ asumP,
                                              const float* __restrict__ mu,
                                              const float* __restrict__ sg,
                                              float* __restrict__ out) {
  // pool aliases: main loop {xs [4][132] | as_ [128][32]} = 4624 floats;
  // epilogue {red_ax 16x136 | red_bx 16x136} = 4352 floats.
  __shared__ float pool[4624];
  __shared__ float sm[32];
  float* xs  = pool;          // stride 132
  float* as_ = pool + 528;    // [n][k] linear: coalesced + broadcast reads
  const int t  = threadIdx.x;
  const int b  = blockIdx.x >> 7;
  const int ft = blockIdx.x & 127;
  const int f0 = ft << 2;
  const int kg = t & 7;
  const int fg = (t >> 3) & 1;
  const int ns = t >> 4;
  const int k4 = kg * 4;
  const int f2 = fg * 2;

  // block-wide asum[b][k] from k_a's 64 n-tile partials
  if (t < 32) {
    float s = 0.f;
#pragma unroll
    for (int nt = 0; nt < 64; ++nt) s += asumP[(b * 64 + nt) * 32 + t];
    sm[t] = s;
  }

  float ax[2][4] = {{0.f}}, bx[2][4] = {{0.f}};
  float xr[2], ar[16];
  // ---- prefetch + store chunk 0 (n = 0..127) ----
#pragma unroll
  for (int it = 0; it < 2; ++it) {
    int flat = t + 256 * it;
    xr[it] = x[(size_t)(b * F_ + f0 + (flat >> 7)) * N_ + (flat & 127)];
  }
#pragma unroll
  for (int it = 0; it < 16; ++it)
    ar[it] = aP[(size_t)b * N_ * K_ + t + 256 * it];
#pragma unroll
  for (int it = 0; it < 2; ++it) {
    int flat = t + 256 * it;
    xs[(flat >> 7) * 132 + (flat & 127)] = xr[it];
  }
#pragma unroll
  for (int it = 0; it < 16; ++it) as_[t + 256 * it] = ar[it];
  __syncthreads();

  for (int c = 0; c < 4; ++c) {
    if (c < 3) {   // prefetch next 128-n chunk into registers
      const int nc = (c + 1) << 7;
#pragma unroll
      for (int it = 0; it < 2; ++it) {
        int flat = t + 256 * it;
        xr[it] = x[(size_t)(b * F_ + f0 + (flat >> 7)) * N_ + nc + (flat & 127)];
      }
#pragma unroll
      for (int it = 0; it < 16; ++it)
        ar[it] = aP[(size_t)b * N_ * K_ + nc * K_ + t + 256 * it];
    }
#pragma unroll
    for (int u = 0; u < 8; ++u) {
      const int n = ns * 8 + u;
      const float4 av = *(const float4*)&as_[n * 32 + k4];
      const float* ap = (const float*)&av;
      const float xv0 = xs[f2 * 132 + n];
      const float xv1 = xs[(f2 + 1) * 132 + n];
      const float xq0 = xv0 * xv0;
      const float xq1 = xv1 * xv1;
#pragma unroll
      for (int j = 0; j < 4; ++j) {
        ax[0][j] += xv0 * ap[j];
        bx[0][j] += xq0 * ap[j];
        ax[1][j] += xv1 * ap[j];
        bx[1][j] += xq1 * ap[j];
      }
    }
    __syncthreads();
    if (c < 3) {
#pragma unroll
      for (int it = 0; it < 2; ++it) {
        int flat = t + 256 * it;
        xs[(flat >> 7) * 132 + (flat & 127)] = xr[it];
      }
#pragma unroll
      for (int it = 0; it < 16; ++it) as_[t + 256 * it] = ar[it];
      __syncthreads();
    }
  }

  // ---- dump ns-partials (pool is free after the last sync) ----
  // plane stride 136 (mod 32 = 8 banks) staggers ns-groups per wave
#pragma unroll
  for (int i = 0; i < 2; ++i) {
    float4 v1, v2;
    v1.x = ax[i][0]; v1.y = ax[i][1]; v1.z = ax[i][2]; v1.w = ax[i][3];
    v2.x = bx[i][0]; v2.y = bx[i][1]; v2.z = bx[i][2]; v2.w = bx[i][3];
    *(float4*)&pool[ns * 136 + (f2 + i) * 32 + k4] = v1;
    *(float4*)&pool[2176 + ns * 136 + (f2 + i) * 32 + k4] = v2;
  }
  __syncthreads();

  // ---- reduce 16 splits; threads t<128 own (f = t>>5, k = t&31) ----
  if (t < 128) {
    const int fr = t >> 5;
    const int kr = t & 31;
    float axv = 0.f, a2v = 0.f;
#pragma unroll
    for (int p = 0; p < 16; ++p) {
      axv += pool[p * 136 + fr * 32 + kr];
      a2v += pool[2176 + p * 136 + fr * 32 + kr];
    }
    const float m  = mu[(f0 + fr) * K_ + kr];
    const float sd = sg[(f0 + fr) * K_ + kr];
    const float as = sm[kr];

    const float fv1 = (axv - m * as) / sd;
    const float fv2 = (a2v - 2.f * m * axv + m * m * as) / (sd * sd) - as;

    float s1 = fv1 * fv1, s2 = fv2 * fv2;
#pragma unroll
    for (int off = 16; off >= 1; off >>= 1) {
      s1 += __shfl_xor(s1, off, 32);
      s2 += __shfl_xor(s2, off, 32);
    }
    const float inv512 = 0.04419417382415922f;  // 1/sqrt(512)
    const float o1 = fv1 / fmaxf(sqrtf(s1), 1e-12f) * inv512;
    const float o2 = fv2 / fmaxf(sqrtf(s2), 1e-12f) * inv512;

    out[(size_t)b * (2 * F_ * K_) + (f0 + fr) * K_ + kr] = o1;
    out[(size_t)b * (2 * F_ * K_) + F_ * K_ + (f0 + fr) * K_ + kr] = o2;
  }
}

extern "C" void kernel_launch(void* const* d_in, const int* in_sizes, int n_in,
                              void* d_out, int out_size, void* d_ws, size_t ws_size,
                              hipStream_t stream) {
  const float* x  = (const float*)d_in[0];
  const float* W  = (const float*)d_in[1];
  const float* bv = (const float*)d_in[2];
  const float* mu = (const float*)d_in[3];
  const float* sg = (const float*)d_in[4];
  float* out = (float*)d_out;

  float* ws    = (float*)d_ws;
  float* aP    = ws;                // 131072 floats
  float* asumP = ws + 131072;       // 16384 floats

  hipLaunchKernelGGL(k_a,    dim3(512),  dim3(256), 0, stream, x, W, bv, aP, asumP);
  hipLaunchKernelGGL(k_axfv, dim3(1024), dim3(256), 0, stream,
                     x, aP, asumP, mu, sg, out);
}